// Round 1
// 78.606 us; speedup vs baseline: 1.0331x; 1.0331x over previous
//
#include <hip/hip_runtime.h>

#define MAXT 100000.0f

constexpr int B    = 64;
constexpr int IN   = 1024;
constexpr int N    = 1025;   // IN + bias column
constexpr int OUTS = 512;
constexpr int NSEG = 16;     // segment-waves per block (1024 threads)
constexpr int SEGL = 64;     // uniform segment length; i=1024 is seg-15 tail
constexpr unsigned KEYMASK = 0xFFFFFC00u;  // top 22 value bits | 10-bit index
constexpr unsigned BIASKEY = 0x3F8003FFu;  // key upper bound for bias rank

struct alignas(8) Pair { unsigned off; unsigned x; };

// ---------------- Fused: per-row sort + gathered-weight scan, 2 j/thread ----
// grid = (B, 4) = 256 blocks -> one block-round on 256 CUs.
// R7 changes vs R6 baseline (81.2 us total, kernel ~20 us of it):
//  * sort: double-buffered ksh -> 1 barrier per cross-wave stage (was 2)
//  * pass 1: float4 loads, lane-halves split rows, shfl_xor(32) combine
//  * pass 2: xn pipelined from ps[] (xsh array deleted)
//  * final reduce: LDS atomicMin on int-reinterpreted nonneg floats
__global__ __launch_bounds__(1024, 4) void snn_fused(
    const float* __restrict__ layer_in,
    const float* __restrict__ weight,
    const float* __restrict__ delay,
    float* __restrict__ out) {
  __shared__ unsigned ksh[2][IN];            // double-buffered sort exchange
  __shared__ float vsh[IN];
  __shared__ __align__(16) Pair ps[N + 1];
  __shared__ float4 red4[NSEG][64];          // pass-1 partials
  __shared__ int redm[128];                  // final min (int bits of nonneg f32)

  const int b    = blockIdx.x;
  const int jc   = blockIdx.y;
  const int lane = threadIdx.x;        // j pair
  const int seg  = threadIdx.y;        // i segment
  const int tid  = seg * 64 + lane;
  const unsigned jadd = (unsigned)((jc * 128 + lane * 2) * 4);  // byte offset

  if (tid < 128) redm[tid] = __float_as_int(MAXT);  // fenced by sort barriers

  // ---- Phase A: scaled input + 1-elem/thread bitonic argsort ----
  {
    float d = delay[tid];
    float v = layer_in[b * IN + tid] * expf(d > 0.0f ? d : 0.0f);
    vsh[tid] = v;                                 // exact x, gathered at end
    unsigned k = (__float_as_uint(v) & KEYMASK) | (unsigned)tid;

    int pb = 0;  // constant-folded by full unroll
#pragma unroll
    for (int kk = 2; kk <= IN; kk <<= 1) {
#pragma unroll
      for (int jj = kk >> 1; jj > 0; jj >>= 1) {
        unsigned other;
        if (jj >= 64) {              // cross-wave exchange via LDS
          // Safe with ONE barrier: stage t+2 writes buffer p only after
          // stage t+1's barrier, which all threads reach only after their
          // stage-t reads of buffer p completed.
          ksh[pb][tid] = k;
          __syncthreads();
          other = ksh[pb][tid ^ jj];
          pb ^= 1;
        } else {                     // in-wave exchange, barrier-free
          other = __shfl_xor(k, jj, 64);
        }
        bool up    = ((tid & kk) == 0);
        bool lower = ((tid & jj) == 0);
        unsigned mn = k < other ? k : other;
        unsigned mx = k < other ? other : k;
        k = (up == lower) ? mn : mx;
      }
    }

    // bias (x=1.0, idx=IN) rank = #elements sorting before it (stable order)
    int r = __syncthreads_count((k <= BIASKEY) ? 1 : 0);

    int idx = (int)(k & 1023u);
    float x = vsh[idx];
    int pos = tid + (tid >= r);
    Pair pr; pr.off = (unsigned)(idx * OUTS * 4); pr.x = __float_as_uint(x);
    ps[pos] = pr;
    if (tid == 0) {
      Pair bias; bias.off = (unsigned)(IN * OUTS * 4); bias.x = __float_as_uint(1.0f);
      ps[r] = bias;
      Pair sent; sent.off = 0u; sent.x = __float_as_uint(MAXT);
      ps[N] = sent;
    }
    __syncthreads();
  }

  // ---- Phase B: segmented scan, first-valid latch, 2 j per thread ----
  const char* wbase = (const char*)weight;
  const int is = seg * SEGL;

  // Pass 1: per-segment partial sums of (w, w*x) via float4, rows split
  // across lane halves (half h takes rows 2*uu+h), combined with shfl_xor(32).
  {
    const int half = lane >> 5;
    const int q    = lane & 31;                       // j-quad index
    const unsigned jadd4 = (unsigned)((jc * 128 + q * 4) * 4);
    float4 sw = make_float4(0.f, 0.f, 0.f, 0.f);
    float4 sx = make_float4(0.f, 0.f, 0.f, 0.f);
#pragma unroll 8
    for (int uu = 0; uu < SEGL / 2; ++uu) {
      Pair p = ps[is + 2 * uu + half];
      float4 w = *(const float4*)(wbase + (p.off + jadd4));
      float xv = __uint_as_float(p.x);
      sw.x += w.x; sw.y += w.y; sw.z += w.z; sw.w += w.w;
      sx.x = fmaf(w.x, xv, sx.x);
      sx.y = fmaf(w.y, xv, sx.y);
      sx.z = fmaf(w.z, xv, sx.z);
      sx.w = fmaf(w.w, xv, sx.w);
    }
    sw.x += __shfl_xor(sw.x, 32, 64);
    sw.y += __shfl_xor(sw.y, 32, 64);
    sw.z += __shfl_xor(sw.z, 32, 64);
    sw.w += __shfl_xor(sw.w, 32, 64);
    sx.x += __shfl_xor(sx.x, 32, 64);
    sx.y += __shfl_xor(sx.y, 32, 64);
    sx.z += __shfl_xor(sx.z, 32, 64);
    sx.w += __shfl_xor(sx.w, 32, 64);
    if (half == 0) {                 // same layout pass 2 expects: per j-pair
      red4[seg][2 * q]     = make_float4(sw.x, sw.y, sx.x, sx.y);
      red4[seg][2 * q + 1] = make_float4(sw.z, sw.w, sx.z, sx.w);
    }
  }
  __syncthreads();

  // Exclusive prefix over segments; wc holds w_cum - 1.
  float wc0 = -1.0f, wc1 = -1.0f, wi0 = 0.0f, wi1 = 0.0f;
  for (int s = 0; s < seg; ++s) {
    float4 t = red4[s][lane];
    wc0 += t.x; wc1 += t.y; wi0 += t.z; wi1 += t.w;
  }

  // Pass 2: latch first valid candidate per j (bd<0 encodes "not found").
  // Valid at step i <=> min3(wc, wi - xi*wc, xn*wc - wi) >= 0; xs sorted =>
  // the first valid candidate IS the filtered min. xn pipelined from ps[].
  float bn0 = MAXT, bd0 = -1.0f, bn1 = MAXT, bd1 = -1.0f;
  Pair p = ps[is];
  float xi = __uint_as_float(p.x);
#pragma unroll 8
  for (int u = 0; u < SEGL; ++u) {
    Pair pn = ps[is + u + 1];
    float2 w = *(const float2*)(wbase + (p.off + jadd));
    float xn = __uint_as_float(pn.x);
    wc0 += w.x;
    wi0 = fmaf(w.x, xi, wi0);
    wc1 += w.y;
    wi1 = fmaf(w.y, xi, wi1);
    float m0 = fminf(fminf(wc0, fmaf(-xi, wc0, wi0)), fmaf(xn, wc0, -wi0));
    float m1 = fminf(fminf(wc1, fmaf(-xi, wc1, wi1)), fmaf(xn, wc1, -wi1));
    bool f0 = (bd0 < 0.0f) & (m0 >= 0.0f);
    bool f1 = (bd1 < 0.0f) & (m1 >= 0.0f);
    bn0 = f0 ? wi0 : bn0;
    bd0 = f0 ? wc0 : bd0;
    bn1 = f1 ? wi1 : bn1;
    bd1 = f1 ? wc1 : bd1;
    p = pn; xi = xn;
  }
  if (seg == NSEG - 1) {                     // tail element i = 1024
    Pair pn = ps[N];                         // sentinel: x = MAXT
    float2 w = *(const float2*)(wbase + (p.off + jadd));
    float xn = __uint_as_float(pn.x);
    wc0 += w.x;
    wi0 = fmaf(w.x, xi, wi0);
    wc1 += w.y;
    wi1 = fmaf(w.y, xi, wi1);
    float m0 = fminf(fminf(wc0, fmaf(-xi, wc0, wi0)), fmaf(xn, wc0, -wi0));
    float m1 = fminf(fminf(wc1, fmaf(-xi, wc1, wi1)), fmaf(xn, wc1, -wi1));
    bool f0 = (bd0 < 0.0f) & (m0 >= 0.0f);
    bool f1 = (bd1 < 0.0f) & (m1 >= 0.0f);
    bn0 = f0 ? wi0 : bn0;
    bd0 = f0 ? wc0 : bd0;
    bn1 = f1 ? wi1 : bn1;
    bd1 = f1 ? wc1 : bd1;
  }
  float best0 = (bd0 < 0.0f) ? MAXT : bn0 * __builtin_amdgcn_rcpf(fmaxf(bd0, 1e-10f));
  float best1 = (bd1 < 0.0f) ? MAXT : bn1 * __builtin_amdgcn_rcpf(fmaxf(bd1, 1e-10f));

  // Final reduce: all candidates are nonneg floats (<= MAXT), so int-bit
  // atomicMin == float min. No extra barrier round, no serial 16-iter loop.
  atomicMin(&redm[lane * 2],     __float_as_int(best0));
  atomicMin(&redm[lane * 2 + 1], __float_as_int(best1));
  __syncthreads();
  if (seg == 0) {
    float2 o = make_float2(__int_as_float(redm[lane * 2]),
                           __int_as_float(redm[lane * 2 + 1]));
    *(float2*)(&out[b * OUTS + jc * 128 + lane * 2]) = o;
  }
}

extern "C" void kernel_launch(void* const* d_in, const int* in_sizes, int n_in,
                              void* d_out, int out_size, void* d_ws, size_t ws_size,
                              hipStream_t stream) {
  const float* layer_in = (const float*)d_in[0];
  const float* weight   = (const float*)d_in[1];
  const float* delay    = (const float*)d_in[2];
  float* out = (float*)d_out;
  (void)d_ws; (void)ws_size;

  snn_fused<<<dim3(B, OUTS / 128), dim3(64, NSEG), 0, stream>>>(
      layer_in, weight, delay, out);
}

// Round 2
// 78.150 us; speedup vs baseline: 1.0392x; 1.0058x over previous
//
#include <hip/hip_runtime.h>

#define MAXT 100000.0f

constexpr int B    = 64;
constexpr int IN   = 1024;
constexpr int N    = 1025;   // IN + bias column
constexpr int OUTS = 512;
constexpr int NSEG = 16;     // segment-waves per block (1024 threads)
constexpr int SEGL = 64;     // uniform segment length; i=1024 is seg-15 tail
constexpr unsigned KEYMASK = 0xFFFFFC00u;  // top 22 value bits | 10-bit index
constexpr unsigned BIASKEY = 0x3F8003FFu;  // key upper bound for bias rank

struct alignas(8) Pair { unsigned off; unsigned x; };
struct alignas(16) Pair2 { Pair a, b; };   // one ds_read_b128

// ---------------- Fused: per-row sort + gathered-weight scan, 2 j/thread ----
// grid = (B, 4) = 256 blocks -> one block-round on 256 CUs.
// R8 changes vs R7 (78.6 us total, kernel ~17 us of it):
//  * pass 2: h-recurrence (g_{u+1} == -h_u exactly) -> 1 fma/col/u saved
//  * pass 2: latch folded to min(m, -bd) >= 0 (input modifier, no SALU)
//  * pass 2: explicit 2-u unroll, ps read as aligned Pair2 (ds_read_b128)
//  * pass 1: seg 15 skipped (its total feeds no exclusive prefix)
__global__ __launch_bounds__(1024, 4) void snn_fused(
    const float* __restrict__ layer_in,
    const float* __restrict__ weight,
    const float* __restrict__ delay,
    float* __restrict__ out) {
  __shared__ unsigned ksh[2][IN];            // double-buffered sort exchange
  __shared__ float vsh[IN];
  __shared__ __align__(16) Pair ps[N + 1];
  __shared__ float4 red4[NSEG][64];          // pass-1 partials
  __shared__ int redm[128];                  // final min (int bits of nonneg f32)

  const int b    = blockIdx.x;
  const int jc   = blockIdx.y;
  const int lane = threadIdx.x;        // j pair
  const int seg  = threadIdx.y;        // i segment
  const int tid  = seg * 64 + lane;
  const unsigned jadd = (unsigned)((jc * 128 + lane * 2) * 4);  // byte offset

  if (tid < 128) redm[tid] = __float_as_int(MAXT);  // fenced by sort barriers

  // ---- Phase A: scaled input + 1-elem/thread bitonic argsort ----
  {
    float d = delay[tid];
    float v = layer_in[b * IN + tid] * expf(d > 0.0f ? d : 0.0f);
    vsh[tid] = v;                                 // exact x, gathered at end
    unsigned k = (__float_as_uint(v) & KEYMASK) | (unsigned)tid;

    int pb = 0;  // constant-folded by full unroll
#pragma unroll
    for (int kk = 2; kk <= IN; kk <<= 1) {
#pragma unroll
      for (int jj = kk >> 1; jj > 0; jj >>= 1) {
        unsigned other;
        if (jj >= 64) {              // cross-wave exchange via LDS
          // Safe with ONE barrier: stage t+2 writes buffer p only after
          // stage t+1's barrier, which all threads reach only after their
          // stage-t reads of buffer p completed.
          ksh[pb][tid] = k;
          __syncthreads();
          other = ksh[pb][tid ^ jj];
          pb ^= 1;
        } else {                     // in-wave exchange, barrier-free
          other = __shfl_xor(k, jj, 64);
        }
        bool up    = ((tid & kk) == 0);
        bool lower = ((tid & jj) == 0);
        unsigned mn = k < other ? k : other;
        unsigned mx = k < other ? other : k;
        k = (up == lower) ? mn : mx;
      }
    }

    // bias (x=1.0, idx=IN) rank = #elements sorting before it (stable order)
    int r = __syncthreads_count((k <= BIASKEY) ? 1 : 0);

    int idx = (int)(k & 1023u);
    float x = vsh[idx];
    int pos = tid + (tid >= r);
    Pair pr; pr.off = (unsigned)(idx * OUTS * 4); pr.x = __float_as_uint(x);
    ps[pos] = pr;
    if (tid == 0) {
      Pair bias; bias.off = (unsigned)(IN * OUTS * 4); bias.x = __float_as_uint(1.0f);
      ps[r] = bias;
      Pair sent; sent.off = 0u; sent.x = __float_as_uint(MAXT);
      ps[N] = sent;
    }
    __syncthreads();
  }

  // ---- Phase B: segmented scan, first-valid latch, 2 j per thread ----
  const char* wbase = (const char*)weight;
  const int is = seg * SEGL;

  // Pass 1: per-segment partial sums of (w, w*x) via float4, rows split
  // across lane halves (half h takes rows 2*uu+h), combined with shfl_xor(32).
  // Seg 15's total feeds no exclusive prefix -> skip (wave-uniform branch).
  if (seg < NSEG - 1) {
    const int half = lane >> 5;
    const int q    = lane & 31;                       // j-quad index
    const unsigned jadd4 = (unsigned)((jc * 128 + q * 4) * 4);
    float4 sw = make_float4(0.f, 0.f, 0.f, 0.f);
    float4 sx = make_float4(0.f, 0.f, 0.f, 0.f);
#pragma unroll 8
    for (int uu = 0; uu < SEGL / 2; ++uu) {
      Pair p = ps[is + 2 * uu + half];
      float4 w = *(const float4*)(wbase + (p.off + jadd4));
      float xv = __uint_as_float(p.x);
      sw.x += w.x; sw.y += w.y; sw.z += w.z; sw.w += w.w;
      sx.x = fmaf(w.x, xv, sx.x);
      sx.y = fmaf(w.y, xv, sx.y);
      sx.z = fmaf(w.z, xv, sx.z);
      sx.w = fmaf(w.w, xv, sx.w);
    }
    sw.x += __shfl_xor(sw.x, 32, 64);
    sw.y += __shfl_xor(sw.y, 32, 64);
    sw.z += __shfl_xor(sw.z, 32, 64);
    sw.w += __shfl_xor(sw.w, 32, 64);
    sx.x += __shfl_xor(sx.x, 32, 64);
    sx.y += __shfl_xor(sx.y, 32, 64);
    sx.z += __shfl_xor(sx.z, 32, 64);
    sx.w += __shfl_xor(sx.w, 32, 64);
    if (half == 0) {                 // same layout pass 2 expects: per j-pair
      red4[seg][2 * q]     = make_float4(sw.x, sw.y, sx.x, sx.y);
      red4[seg][2 * q + 1] = make_float4(sw.z, sw.w, sx.z, sx.w);
    }
  }
  __syncthreads();

  // Exclusive prefix over segments; wc holds w_cum - 1.
  float wc0 = -1.0f, wc1 = -1.0f, wi0 = 0.0f, wi1 = 0.0f;
  for (int s = 0; s < seg; ++s) {
    float4 t = red4[s][lane];
    wc0 += t.x; wc1 += t.y; wi0 += t.z; wi1 += t.w;
  }

  // Pass 2: latch first valid candidate per j (bd<0 encodes "not found").
  // valid(u) <=> min3(wc_u, -h_{u-1}, h_u) >= 0 with h_u = x_{u+1}*wc_u - wi_u
  // (identity: g_{u+1} = wi - x*wc quantity == -h_u exactly). xs sorted =>
  // first valid IS the filtered min. Latch test folded: min(m, -bd) >= 0.
  float bn0 = MAXT, bd0 = -1.0f, bn1 = MAXT, bd1 = -1.0f;
  Pair pa, pb;
  { Pair2 t = *(const Pair2*)(ps + is); pa = t.a; pb = t.b; }
  float hp0, hp1;
  {
    float x0 = __uint_as_float(pa.x);
    hp0 = fmaf(x0, wc0, -wi0);     // -g at segment start
    hp1 = fmaf(x0, wc1, -wi1);
  }
#pragma unroll 4
  for (int u = 0; u < SEGL; u += 2) {
    Pair2 nx = *(const Pair2*)(ps + is + u + 2);   // ds_read_b128, 16-aligned
    {
      float2 w = *(const float2*)(wbase + (pa.off + jadd));
      float xi = __uint_as_float(pa.x);
      float xn = __uint_as_float(pb.x);
      wc0 += w.x; wi0 = fmaf(w.x, xi, wi0);
      wc1 += w.y; wi1 = fmaf(w.y, xi, wi1);
      float h0 = fmaf(xn, wc0, -wi0);
      float h1 = fmaf(xn, wc1, -wi1);
      float q0 = fminf(fminf(fminf(wc0, -hp0), h0), -bd0);
      float q1 = fminf(fminf(fminf(wc1, -hp1), h1), -bd1);
      bool f0 = q0 >= 0.0f;
      bool f1 = q1 >= 0.0f;
      bn0 = f0 ? wi0 : bn0;  bd0 = f0 ? wc0 : bd0;
      bn1 = f1 ? wi1 : bn1;  bd1 = f1 ? wc1 : bd1;
      hp0 = h0; hp1 = h1;
    }
    {
      float2 w = *(const float2*)(wbase + (pb.off + jadd));
      float xi = __uint_as_float(pb.x);
      float xn = __uint_as_float(nx.a.x);
      wc0 += w.x; wi0 = fmaf(w.x, xi, wi0);
      wc1 += w.y; wi1 = fmaf(w.y, xi, wi1);
      float h0 = fmaf(xn, wc0, -wi0);
      float h1 = fmaf(xn, wc1, -wi1);
      float q0 = fminf(fminf(fminf(wc0, -hp0), h0), -bd0);
      float q1 = fminf(fminf(fminf(wc1, -hp1), h1), -bd1);
      bool f0 = q0 >= 0.0f;
      bool f1 = q1 >= 0.0f;
      bn0 = f0 ? wi0 : bn0;  bd0 = f0 ? wc0 : bd0;
      bn1 = f1 ? wi1 : bn1;  bd1 = f1 ? wc1 : bd1;
      hp0 = h0; hp1 = h1;
    }
    pa = nx.a; pb = nx.b;
  }
  if (seg == NSEG - 1) {                     // tail element i = 1024
    // loop exit carries pa = ps[1024], pb = ps[1025] (MAXT sentinel)
    float2 w = *(const float2*)(wbase + (pa.off + jadd));
    float xi = __uint_as_float(pa.x);
    float xn = __uint_as_float(pb.x);
    wc0 += w.x; wi0 = fmaf(w.x, xi, wi0);
    wc1 += w.y; wi1 = fmaf(w.y, xi, wi1);
    float h0 = fmaf(xn, wc0, -wi0);
    float h1 = fmaf(xn, wc1, -wi1);
    float q0 = fminf(fminf(fminf(wc0, -hp0), h0), -bd0);
    float q1 = fminf(fminf(fminf(wc1, -hp1), h1), -bd1);
    bool f0 = q0 >= 0.0f;
    bool f1 = q1 >= 0.0f;
    bn0 = f0 ? wi0 : bn0;  bd0 = f0 ? wc0 : bd0;
    bn1 = f1 ? wi1 : bn1;  bd1 = f1 ? wc1 : bd1;
  }
  float best0 = (bd0 < 0.0f) ? MAXT : bn0 * __builtin_amdgcn_rcpf(fmaxf(bd0, 1e-10f));
  float best1 = (bd1 < 0.0f) ? MAXT : bn1 * __builtin_amdgcn_rcpf(fmaxf(bd1, 1e-10f));

  // Final reduce: all candidates are nonneg floats (<= MAXT), so int-bit
  // atomicMin == float min. No extra barrier round, no serial 16-iter loop.
  atomicMin(&redm[lane * 2],     __float_as_int(best0));
  atomicMin(&redm[lane * 2 + 1], __float_as_int(best1));
  __syncthreads();
  if (seg == 0) {
    float2 o = make_float2(__int_as_float(redm[lane * 2]),
                           __int_as_float(redm[lane * 2 + 1]));
    *(float2*)(&out[b * OUTS + jc * 128 + lane * 2]) = o;
  }
}

extern "C" void kernel_launch(void* const* d_in, const int* in_sizes, int n_in,
                              void* d_out, int out_size, void* d_ws, size_t ws_size,
                              hipStream_t stream) {
  const float* layer_in = (const float*)d_in[0];
  const float* weight   = (const float*)d_in[1];
  const float* delay    = (const float*)d_in[2];
  float* out = (float*)d_out;
  (void)d_ws; (void)ws_size;

  snn_fused<<<dim3(B, OUTS / 128), dim3(64, NSEG), 0, stream>>>(
      layer_in, weight, delay, out);
}